// Round 7
// baseline (325.014 us; speedup 1.0000x reference)
//
#include <hip/hip_runtime.h>
#include <hip/hip_bf16.h>

#define SEQ 2048
#define BSZ 2
#define DIM 1024
#define NH 16
#define HD 64
#define WIN 8
#define PN 256

typedef __hip_bfloat16 bf16;
typedef __attribute__((ext_vector_type(8))) short short8;
typedef __attribute__((ext_vector_type(4))) float f32x4;

__device__ __forceinline__ float b2f(bf16 x) { return __bfloat162float(x); }
__device__ __forceinline__ bf16 f2b(float x) { return __float2bfloat16(x); }
__device__ __forceinline__ short fbits(float x) { bf16 h = __float2bfloat16(x); return *(short*)&h; }

// async global->LDS, 16B per lane; LDS dest must be wave-uniform base + lane*16
__device__ __forceinline__ void gl_lds16(const bf16* g, bf16* l) {
    __builtin_amdgcn_global_load_lds((const __attribute__((address_space(1))) void*)g,
                                     (__attribute__((address_space(3))) void*)l, 16, 0, 0);
}

// ---------------------------------------------------------------------------
// fp32 -> bf16 pre-convert: query (4M) + 6 weights (6M) + bias pack (6K fp32)
// ---------------------------------------------------------------------------
__global__ void convert_kernel(const float* __restrict__ q,
                               const float* __restrict__ w0, const float* __restrict__ w1,
                               const float* __restrict__ w2, const float* __restrict__ w3,
                               const float* __restrict__ w4, const float* __restrict__ w5,
                               const float* __restrict__ b0, const float* __restrict__ b1,
                               const float* __restrict__ b2, const float* __restrict__ b3,
                               const float* __restrict__ b4, const float* __restrict__ b5,
                               bf16* __restrict__ qbf, bf16* __restrict__ wbf,
                               float* __restrict__ bp) {
    int i = blockIdx.x * 256 + threadIdx.x;          // vector idx, 8 floats each
    const int QV = (SEQ * BSZ * DIM) / 8;            // 524288
    const int WV = (DIM * DIM) / 8;                  // 131072
    const int TV = QV + 6 * WV;
    if (i >= TV) {                                   // bias path: 768 chunks
        int j = i - TV;
        if (j >= 768) return;
        int mat = j >> 7, k = (j & 127) * 8;
        const float* s = (mat == 0) ? b0 : (mat == 1) ? b1 : (mat == 2) ? b2
                       : (mat == 3) ? b3 : (mat == 4) ? b4 : b5;
        *(f32x4*)(bp + mat * DIM + k)     = *(const f32x4*)(s + k);
        *(f32x4*)(bp + mat * DIM + k + 4) = *(const f32x4*)(s + k + 4);
        return;
    }
    const float* src;
    bf16* dst;
    size_t off;
    if (i < QV) { src = q; dst = qbf; off = (size_t)i * 8; }
    else {
        int j = i - QV;
        int mat = j / WV, k = j - mat * WV;
        src = (mat == 0) ? w0 : (mat == 1) ? w1 : (mat == 2) ? w2
            : (mat == 3) ? w3 : (mat == 4) ? w4 : w5;
        dst = wbf + (size_t)mat * DIM * DIM;
        off = (size_t)k * 8;
    }
    f32x4 av4 = *(const f32x4*)(src + off);
    f32x4 bv4 = *(const f32x4*)(src + off + 4);
    short8 o;
#pragma unroll
    for (int e = 0; e < 4; ++e) { o[e] = fbits(av4[e]); o[e + 4] = fbits(bv4[e]); }
    *(short8*)(dst + off) = o;
}

// ---------------------------------------------------------------------------
// phrase[(p*BSZ+b)*DIM+d] = max_{w<8} query[(8p+w)][b][d]   (fp32 in, bf16 out)
// ---------------------------------------------------------------------------
__global__ void phrase_max_kernel(const float* __restrict__ q, bf16* __restrict__ phrase) {
    int idx = blockIdx.x * 256 + threadIdx.x;
    int d  = idx % DIM;
    int pb = idx / DIM;
    int b  = pb % BSZ;
    int p  = pb / BSZ;
    float m = -1e30f;
#pragma unroll
    for (int w = 0; w < WIN; ++w)
        m = fmaxf(m, q[((size_t)(p * WIN + w) * BSZ + b) * DIM + d]);
    phrase[idx] = f2b(m);
}

// ---------------------------------------------------------------------------
// gvT[bh*HD+hd][p] = sum_j gauss(p,j) * vT[bh*HD+hd][j], banded |j-mu|<=15.5
// ---------------------------------------------------------------------------
__global__ void gauss_v_kernel(const bf16* __restrict__ vT, bf16* __restrict__ gvT) {
    int row = blockIdx.x;               // bh*HD + hd
    int p   = threadIdx.x;              // 0..255
    float mu = p * (float)WIN + (WIN - 1) * 0.5f;
    float acc = 0.f;
    int j0 = p * WIN - 12;
    const bf16* src = vT + (size_t)row * SEQ;
#pragma unroll
    for (int jj = 0; jj < 32; ++jj) {
        int j = j0 + jj;
        if (j < 0 || j >= SEQ) continue;
        float dd = (float)j - mu;
        acc += __expf(-dd * dd * 0.125f) * 0.199471140200716f * b2f(src[j]);
    }
    gvT[(size_t)row * PN + p] = f2b(acc);
}

// ---------------------------------------------------------------------------
// Shared GEMM body (m97 pattern): C = (A @ Wtile^T + bias) * scale
// bf16 in via global_load_lds(16B), fp32 MFMA accum, LDS [128][32] unpadded.
// modes: 0 head-scatter bf16, 1 direct fp32, 2 transposed head-scatter bf16.
// ---------------------------------------------------------------------------
__device__ __forceinline__ void gemm_body(const bf16* __restrict__ A,
                                          const bf16* __restrict__ W,
                                          const float* __restrict__ bias,
                                          void* __restrict__ Cout,
                                          int m0, int n0, float scale,
                                          int mode, int LEN) {
    __shared__ bf16 As[128 * 32];
    __shared__ bf16 Ws[128 * 32];
    int t = threadIdx.x;
    int wave = t >> 6, lane = t & 63;
    int wm = (wave >> 1) * 64, wn = (wave & 1) * 64;
    int l15 = lane & 15, quad = lane >> 4;

    f32x4 acc[4][4] = {};

    for (int k0 = 0; k0 < DIM; k0 += 32) {
        {
            int c0 = t, c1 = t + 256;
            gl_lds16(A + (size_t)(m0 + (c0 >> 2)) * DIM + k0 + (c0 & 3) * 8, &As[c0 * 8]);
            gl_lds16(A + (size_t)(m0 + (c1 >> 2)) * DIM + k0 + (c1 & 3) * 8, &As[c1 * 8]);
            gl_lds16(W + (size_t)(n0 + (c0 >> 2)) * DIM + k0 + (c0 & 3) * 8, &Ws[c0 * 8]);
            gl_lds16(W + (size_t)(n0 + (c1 >> 2)) * DIM + k0 + (c1 & 3) * 8, &Ws[c1 * 8]);
        }
        __syncthreads();
        short8 af[4], bfr[4];
#pragma unroll
        for (int tm = 0; tm < 4; ++tm)
            af[tm] = *(short8*)&As[(wm + tm * 16 + l15) * 32 + quad * 8];
#pragma unroll
        for (int tn = 0; tn < 4; ++tn)
            bfr[tn] = *(short8*)&Ws[(wn + tn * 16 + l15) * 32 + quad * 8];
#pragma unroll
        for (int tm = 0; tm < 4; ++tm)
#pragma unroll
            for (int tn = 0; tn < 4; ++tn)
                acc[tm][tn] = __builtin_amdgcn_mfma_f32_16x16x32_bf16(af[tm], bfr[tn], acc[tm][tn], 0, 0, 0);
        __syncthreads();
    }

#pragma unroll
    for (int tm = 0; tm < 4; ++tm) {
        int mrow = m0 + wm + tm * 16 + quad * 4;
#pragma unroll
        for (int tn = 0; tn < 4; ++tn) {
            int n = n0 + wn + tn * 16 + l15;
            float bsv = bias[n];
#pragma unroll
            for (int r = 0; r < 4; ++r) {
                int m = mrow + r;
                float val = (acc[tm][tn][r] + bsv) * scale;
                if (mode == 0) {
                    int s = m / BSZ, b = m % BSZ;
                    int h = n >> 6, hd = n & 63;
                    ((bf16*)Cout)[((size_t)(b * NH + h) * LEN + s) * HD + hd] = f2b(val);
                } else if (mode == 2) {
                    int s = m / BSZ, b = m % BSZ;
                    int h = n >> 6, hd = n & 63;
                    ((bf16*)Cout)[((size_t)(b * NH + h) * HD + hd) * LEN + s] = f2b(val);
                } else {
                    ((float*)Cout)[(size_t)m * DIM + n] = val;
                }
            }
        }
    }
}

#define QSCALE (0.125f * 1.44269504088896f)   // fold log2(e) for exp2

// batched projections: z = 0:q_b 1:k_b 2:vT 3:q_g 4:k_g(phrase)
__global__ __launch_bounds__(256) void gemm_proj(const bf16* __restrict__ qbf,
                                                 const bf16* __restrict__ phrasebf,
                                                 const bf16* __restrict__ wbf,
                                                 const float* __restrict__ bias_pack,
                                                 bf16* __restrict__ q_b, bf16* __restrict__ k_b,
                                                 bf16* __restrict__ vT, bf16* __restrict__ q_g,
                                                 bf16* __restrict__ k_g) {
    int z = blockIdx.z;
    const bf16* A = qbf;
    bf16* C;
    int mode = 0, LEN = SEQ;
    float scale = 1.0f;
    switch (z) {
        case 0: C = q_b; scale = QSCALE; break;
        case 1: C = k_b; break;
        case 2: C = vT; mode = 2; break;
        case 3: C = q_g; scale = QSCALE; break;
        default:
            if (blockIdx.x >= 4) return;          // M = 512 for phrase GEMM
            A = phrasebf; C = k_g; LEN = PN; break;
    }
    gemm_body(A, wbf + (size_t)z * DIM * DIM, bias_pack + z * DIM, C,
              blockIdx.x * 128, blockIdx.y * 128, scale, mode, LEN);
}

__global__ __launch_bounds__(256) void gemm_final(const bf16* __restrict__ attn_bf,
                                                  const bf16* __restrict__ wbf,
                                                  const float* __restrict__ bias_pack,
                                                  float* __restrict__ out) {
    gemm_body(attn_bf, wbf + (size_t)5 * DIM * DIM, bias_pack + 5 * DIM, out,
              blockIdx.x * 128, blockIdx.y * 128, 1.0f, 1, SEQ);
}

// ---------------------------------------------------------------------------
// MFMA attention v2: block = (b,h) x 128 q-rows, 4 waves x 32 rows (2 m-tiles).
// B-fragments (K,V) reused across both m-tiles; K/V staging software-pipelined
// (prefetch next chunk into VGPRs during compute).
//   phase 0: gauss branch over PN phrase keys; phase 1: base over SEQ keys.
// Writes attn_bf bf16 [m=s*BSZ+b][h*64+hd].
// ---------------------------------------------------------------------------
__global__ __launch_bounds__(256) void attn_kernel(const bf16* __restrict__ qb,
                                                   const bf16* __restrict__ kb,
                                                   const bf16* __restrict__ vT,
                                                   const bf16* __restrict__ qg,
                                                   const bf16* __restrict__ kg,
                                                   const bf16* __restrict__ gvT,
                                                   bf16* __restrict__ out) {
    __shared__ bf16 Qs[128][72];   // [qrow][hd]
    __shared__ bf16 Ks[64][72];    // [key][hd]
    __shared__ bf16 Vt[64][72];    // [hd][key]
    __shared__ bf16 Ps[128][72];   // [qrow][key]

    int t = threadIdx.x;
    int wave = t >> 6, lane = t & 63;
    int l15 = lane & 15, quad = lane >> 4;
    int q0 = blockIdx.x * 128;
    int bh = blockIdx.y;
    int b = bh / NH, h = bh % NH;

    const short8 ones = (short8)0x3F80;   // bf16 1.0 splat

    float result[2][4][4] = {};           // [m-tile][n-tile][row]

    for (int phase = 0; phase < 2; ++phase) {
        const bf16* qptr = phase ? qb : qg;
        const bf16* kptr = phase ? kb : kg;
        const bf16* vtp  = phase ? vT : gvT;
        int kvlen = phase ? SEQ : PN;
        int nchunk = kvlen / 64;

        __syncthreads();   // prior phase's Qs reads done
        {
            int r = t >> 1, c0 = (t & 1) * 32;
            const bf16* qsrc = qptr + ((size_t)bh * SEQ + q0 + r) * HD + c0;
#pragma unroll
            for (int e = 0; e < 4; ++e)
                *(short8*)&Qs[r][c0 + e * 8] = *(const short8*)(qsrc + e * 8);
        }

        // staging addresses (r = key idx for K, hd idx for V)
        int sr = t >> 2, sc = (t & 3) * 16;
        const bf16* kbase = kptr + ((size_t)bh * kvlen + sr) * HD + sc;
        const bf16* vbase = vtp + (size_t)(bh * HD + sr) * kvlen + sc;

        // prefetch chunk 0
        short8 kr0, kr1, vr0, vr1;
        kr0 = *(const short8*)(kbase);
        kr1 = *(const short8*)(kbase + 8);
        vr0 = *(const short8*)(vbase);
        vr1 = *(const short8*)(vbase + 8);

        f32x4 o_acc[2][4] = {};
        f32x4 l_acc[2] = {};
        for (int ch = 0; ch < nchunk; ++ch) {
            __syncthreads();   // prev chunk's K/V reads done (and Q staged, 1st)
            *(short8*)&Ks[sr][sc]     = kr0;
            *(short8*)&Ks[sr][sc + 8] = kr1;
            *(short8*)&Vt[sr][sc]     = vr0;
            *(short8*)&Vt[sr][sc + 8] = vr1;
            if (ch + 1 < nchunk) {     // prefetch next (in flight over compute)
                const bf16* kn = kbase + (size_t)(ch + 1) * 64 * HD;
                const bf16* vn = vbase + (ch + 1) * 64;
                kr0 = *(const short8*)(kn);
                kr1 = *(const short8*)(kn + 8);
                vr0 = *(const short8*)(vn);
                vr1 = *(const short8*)(vn + 8);
            }
            __syncthreads();

            // S = Q K^T : 2 m-tiles x 64 keys per wave
            f32x4 s_acc[2][4] = {};
#pragma unroll
            for (int kk = 0; kk < 2; ++kk) {
                short8 a0 = *(short8*)&Qs[wave * 32 + l15][kk * 32 + quad * 8];
                short8 a1 = *(short8*)&Qs[wave * 32 + 16 + l15][kk * 32 + quad * 8];
#pragma unroll
                for (int tn = 0; tn < 4; ++tn) {
                    short8 bb = *(short8*)&Ks[tn * 16 + l15][kk * 32 + quad * 8];
                    s_acc[0][tn] = __builtin_amdgcn_mfma_f32_16x16x32_bf16(a0, bb, s_acc[0][tn], 0, 0, 0);
                    s_acc[1][tn] = __builtin_amdgcn_mfma_f32_16x16x32_bf16(a1, bb, s_acc[1][tn], 0, 0, 0);
                }
            }
            // P = exp2(S), C-layout scatter to Ps (own rows only -> no barrier)
#pragma unroll
            for (int m = 0; m < 2; ++m)
#pragma unroll
                for (int tn = 0; tn < 4; ++tn)
#pragma unroll
                    for (int r = 0; r < 4; ++r)
                        Ps[wave * 32 + m * 16 + quad * 4 + r][tn * 16 + l15] =
                            f2b(exp2f(fminf(s_acc[m][tn][r], 43.f)));
            // PV + rowsum
#pragma unroll
            for (int kk = 0; kk < 2; ++kk) {
                short8 pa0 = *(short8*)&Ps[wave * 32 + l15][kk * 32 + quad * 8];
                short8 pa1 = *(short8*)&Ps[wave * 32 + 16 + l15][kk * 32 + quad * 8];
                l_acc[0] = __builtin_amdgcn_mfma_f32_16x16x32_bf16(pa0, ones, l_acc[0], 0, 0, 0);
                l_acc[1] = __builtin_amdgcn_mfma_f32_16x16x32_bf16(pa1, ones, l_acc[1], 0, 0, 0);
#pragma unroll
                for (int tn = 0; tn < 4; ++tn) {
                    short8 vb = *(short8*)&Vt[tn * 16 + l15][kk * 32 + quad * 8];
                    o_acc[0][tn] = __builtin_amdgcn_mfma_f32_16x16x32_bf16(pa0, vb, o_acc[0][tn], 0, 0, 0);
                    o_acc[1][tn] = __builtin_amdgcn_mfma_f32_16x16x32_bf16(pa1, vb, o_acc[1][tn], 0, 0, 0);
                }
            }
        }
#pragma unroll
        for (int m = 0; m < 2; ++m)
#pragma unroll
            for (int r = 0; r < 4; ++r) {
                float inv = 0.5f / fmaxf(l_acc[m][r], 1e-30f);
#pragma unroll
                for (int tn = 0; tn < 4; ++tn)
                    result[m][tn][r] += o_acc[m][tn][r] * inv;
            }
    }

#pragma unroll
    for (int m = 0; m < 2; ++m)
#pragma unroll
        for (int r = 0; r < 4; ++r) {
            int srow = q0 + wave * 32 + m * 16 + quad * 4 + r;
            int mm = srow * BSZ + b;
#pragma unroll
            for (int tn = 0; tn < 4; ++tn) {
                int dcol = h * HD + tn * 16 + l15;
                out[(size_t)mm * DIM + dcol] = f2b(result[m][tn][r]);
            }
        }
}

// ---------------------------------------------------------------------------
extern "C" void kernel_launch(void* const* d_in, const int* in_sizes, int n_in,
                              void* d_out, int out_size, void* d_ws, size_t ws_size,
                              hipStream_t stream) {
    (void)in_sizes; (void)n_in; (void)out_size; (void)ws_size;
    const float* query = (const float*)d_in[0];
    const float* Wq_b  = (const float*)d_in[1];
    const float* bq_b  = (const float*)d_in[2];
    const float* Wk_b  = (const float*)d_in[3];
    const float* bk_b  = (const float*)d_in[4];
    const float* Wq_g  = (const float*)d_in[5];
    const float* bq_g  = (const float*)d_in[6];
    const float* Wk_g  = (const float*)d_in[7];
    const float* bk_g  = (const float*)d_in[8];
    const float* Wv    = (const float*)d_in[9];
    const float* bv    = (const float*)d_in[10];
    const float* Wo    = (const float*)d_in[11];
    const float* bo    = (const float*)d_in[12];
    float* out = (float*)d_out;

    const size_t NQ = (size_t)BSZ * NH * SEQ * HD;   // 4194304
    const size_t NP = (size_t)BSZ * NH * PN * HD;    // 524288
    bf16* qbf      = (bf16*)d_ws;                    // 4M
    bf16* wbf      = qbf + NQ;                       // 6M
    bf16* phrasebf = wbf + (size_t)6 * DIM * DIM;    // 512K
    bf16* q_b      = phrasebf + (size_t)PN * BSZ * DIM;
    bf16* k_b      = q_b + NQ;
    bf16* vT       = k_b + NQ;                       // [bh][hd][s]
    bf16* q_g      = vT + NQ;
    bf16* k_g      = q_g + NQ;                       // [bh][p][hd]
    bf16* gvT      = k_g + NP;                       // [bh][hd][p]
    bf16* attn_bf  = gvT + NP;                       // [m][dcol]
    float* bias_pack = (float*)(attn_bf + NQ);       // 6*1024 fp32

    const int QV = (SEQ * BSZ * DIM) / 8, WV6 = 6 * (DIM * DIM) / 8;
    convert_kernel<<<(QV + WV6) / 256 + 3, 256, 0, stream>>>(
        query, Wq_b, Wk_b, Wv, Wq_g, Wk_g, Wo,
        bq_b, bk_b, bv, bq_g, bk_g, bo, qbf, wbf, bias_pack);
    phrase_max_kernel<<<(PN * BSZ * DIM) / 256, 256, 0, stream>>>(query, phrasebf);

    dim3 gp((SEQ * BSZ) / 128, DIM / 128, 5);
    gemm_proj<<<gp, 256, 0, stream>>>(qbf, phrasebf, wbf, bias_pack,
                                      q_b, k_b, vT, q_g, k_g);

    gauss_v_kernel<<<BSZ * NH * HD, PN, 0, stream>>>(vT, gvT);

    dim3 g3(SEQ / 128, BSZ * NH);
    attn_kernel<<<g3, 256, 0, stream>>>(q_b, k_b, vT, q_g, k_g, gvT, attn_bf);

    dim3 gf((SEQ * BSZ) / 128, DIM / 128);
    gemm_final<<<gf, 256, 0, stream>>>(attn_bf, wbf, bias_pack, out);
}

// Round 8
// 295.262 us; speedup vs baseline: 1.1008x; 1.1008x over previous
//
#include <hip/hip_runtime.h>
#include <hip/hip_bf16.h>

#define SEQ 2048
#define BSZ 2
#define DIM 1024
#define NH 16
#define HD 64
#define WIN 8
#define PN 256

typedef __hip_bfloat16 bf16;
typedef __attribute__((ext_vector_type(8))) short short8;
typedef __attribute__((ext_vector_type(4))) short short4v;
typedef __attribute__((ext_vector_type(4))) float f32x4;

__device__ __forceinline__ float b2f(bf16 x) { return __bfloat162float(x); }
__device__ __forceinline__ bf16 f2b(float x) { return __float2bfloat16(x); }
__device__ __forceinline__ short fbits(float x) { bf16 h = __float2bfloat16(x); return *(short*)&h; }

// async global->LDS, 16B per lane; LDS dest must be wave-uniform base + lane*16
__device__ __forceinline__ void gl_lds16(const bf16* g, bf16* l) {
    __builtin_amdgcn_global_load_lds((const __attribute__((address_space(1))) void*)g,
                                     (__attribute__((address_space(3))) void*)l, 16, 0, 0);
}

// ---------------------------------------------------------------------------
// fp32 -> bf16 pre-convert: query (4M) + 6 weights (6M) + bias pack (6K fp32)
// ---------------------------------------------------------------------------
__global__ void convert_kernel(const float* __restrict__ q,
                               const float* __restrict__ w0, const float* __restrict__ w1,
                               const float* __restrict__ w2, const float* __restrict__ w3,
                               const float* __restrict__ w4, const float* __restrict__ w5,
                               const float* __restrict__ b0, const float* __restrict__ b1,
                               const float* __restrict__ b2, const float* __restrict__ b3,
                               const float* __restrict__ b4, const float* __restrict__ b5,
                               bf16* __restrict__ qbf, bf16* __restrict__ wbf,
                               float* __restrict__ bp) {
    int i = blockIdx.x * 256 + threadIdx.x;          // vector idx, 8 floats each
    const int QV = (SEQ * BSZ * DIM) / 8;            // 524288
    const int WV = (DIM * DIM) / 8;                  // 131072
    const int TV = QV + 6 * WV;
    if (i >= TV) {                                   // bias path: 768 chunks
        int j = i - TV;
        if (j >= 768) return;
        int mat = j >> 7, k = (j & 127) * 8;
        const float* s = (mat == 0) ? b0 : (mat == 1) ? b1 : (mat == 2) ? b2
                       : (mat == 3) ? b3 : (mat == 4) ? b4 : b5;
        *(f32x4*)(bp + mat * DIM + k)     = *(const f32x4*)(s + k);
        *(f32x4*)(bp + mat * DIM + k + 4) = *(const f32x4*)(s + k + 4);
        return;
    }
    const float* src;
    bf16* dst;
    size_t off;
    if (i < QV) { src = q; dst = qbf; off = (size_t)i * 8; }
    else {
        int j = i - QV;
        int mat = j / WV, k = j - mat * WV;
        src = (mat == 0) ? w0 : (mat == 1) ? w1 : (mat == 2) ? w2
            : (mat == 3) ? w3 : (mat == 4) ? w4 : w5;
        dst = wbf + (size_t)mat * DIM * DIM;
        off = (size_t)k * 8;
    }
    f32x4 av4 = *(const f32x4*)(src + off);
    f32x4 bv4 = *(const f32x4*)(src + off + 4);
    short8 o;
#pragma unroll
    for (int e = 0; e < 4; ++e) { o[e] = fbits(av4[e]); o[e + 4] = fbits(bv4[e]); }
    *(short8*)(dst + off) = o;
}

// ---------------------------------------------------------------------------
// phrase[(p*BSZ+b)*DIM+d] = max_{w<8} query[(8p+w)][b][d]   (fp32 in, bf16 out)
// ---------------------------------------------------------------------------
__global__ void phrase_max_kernel(const float* __restrict__ q, bf16* __restrict__ phrase) {
    int idx = blockIdx.x * 256 + threadIdx.x;
    int d  = idx % DIM;
    int pb = idx / DIM;
    int b  = pb % BSZ;
    int p  = pb / BSZ;
    float m = -1e30f;
#pragma unroll
    for (int w = 0; w < WIN; ++w)
        m = fmaxf(m, q[((size_t)(p * WIN + w) * BSZ + b) * DIM + d]);
    phrase[idx] = f2b(m);
}

// ---------------------------------------------------------------------------
// gvT[bh*HD+hd][p] = sum_j gauss(p,j) * vT[bh*HD+hd][j], banded |j-mu|<=15.5
// ---------------------------------------------------------------------------
__global__ void gauss_v_kernel(const bf16* __restrict__ vT, bf16* __restrict__ gvT) {
    int row = blockIdx.x;               // bh*HD + hd
    int p   = threadIdx.x;              // 0..255
    float mu = p * (float)WIN + (WIN - 1) * 0.5f;
    float acc = 0.f;
    int j0 = p * WIN - 12;
    const bf16* src = vT + (size_t)row * SEQ;
#pragma unroll
    for (int jj = 0; jj < 32; ++jj) {
        int j = j0 + jj;
        if (j < 0 || j >= SEQ) continue;
        float dd = (float)j - mu;
        acc += __expf(-dd * dd * 0.125f) * 0.199471140200716f * b2f(src[j]);
    }
    gvT[(size_t)row * PN + p] = f2b(acc);
}

// ---------------------------------------------------------------------------
// Shared GEMM body (m97 pattern): C = (A @ Wtile^T + bias) * scale
// bf16 in via global_load_lds(16B), fp32 MFMA accum, LDS [128][32] unpadded.
// modes: 0 head-scatter bf16, 1 direct fp32, 2 transposed head-scatter bf16.
// ---------------------------------------------------------------------------
__device__ __forceinline__ void gemm_body(const bf16* __restrict__ A,
                                          const bf16* __restrict__ W,
                                          const float* __restrict__ bias,
                                          void* __restrict__ Cout,
                                          int m0, int n0, float scale,
                                          int mode, int LEN) {
    __shared__ bf16 As[128 * 32];
    __shared__ bf16 Ws[128 * 32];
    int t = threadIdx.x;
    int wave = t >> 6, lane = t & 63;
    int wm = (wave >> 1) * 64, wn = (wave & 1) * 64;
    int l15 = lane & 15, quad = lane >> 4;

    f32x4 acc[4][4] = {};

    for (int k0 = 0; k0 < DIM; k0 += 32) {
        {
            int c0 = t, c1 = t + 256;
            gl_lds16(A + (size_t)(m0 + (c0 >> 2)) * DIM + k0 + (c0 & 3) * 8, &As[c0 * 8]);
            gl_lds16(A + (size_t)(m0 + (c1 >> 2)) * DIM + k0 + (c1 & 3) * 8, &As[c1 * 8]);
            gl_lds16(W + (size_t)(n0 + (c0 >> 2)) * DIM + k0 + (c0 & 3) * 8, &Ws[c0 * 8]);
            gl_lds16(W + (size_t)(n0 + (c1 >> 2)) * DIM + k0 + (c1 & 3) * 8, &Ws[c1 * 8]);
        }
        __syncthreads();
        short8 af[4], bfr[4];
#pragma unroll
        for (int tm = 0; tm < 4; ++tm)
            af[tm] = *(short8*)&As[(wm + tm * 16 + l15) * 32 + quad * 8];
#pragma unroll
        for (int tn = 0; tn < 4; ++tn)
            bfr[tn] = *(short8*)&Ws[(wn + tn * 16 + l15) * 32 + quad * 8];
#pragma unroll
        for (int tm = 0; tm < 4; ++tm)
#pragma unroll
            for (int tn = 0; tn < 4; ++tn)
                acc[tm][tn] = __builtin_amdgcn_mfma_f32_16x16x32_bf16(af[tm], bfr[tn], acc[tm][tn], 0, 0, 0);
        __syncthreads();
    }

#pragma unroll
    for (int tm = 0; tm < 4; ++tm) {
        int mrow = m0 + wm + tm * 16 + quad * 4;
#pragma unroll
        for (int tn = 0; tn < 4; ++tn) {
            int n = n0 + wn + tn * 16 + l15;
            float bsv = bias[n];
#pragma unroll
            for (int r = 0; r < 4; ++r) {
                int m = mrow + r;
                float val = (acc[tm][tn][r] + bsv) * scale;
                if (mode == 0) {
                    int s = m / BSZ, b = m % BSZ;
                    int h = n >> 6, hd = n & 63;
                    ((bf16*)Cout)[((size_t)(b * NH + h) * LEN + s) * HD + hd] = f2b(val);
                } else if (mode == 2) {
                    int s = m / BSZ, b = m % BSZ;
                    int h = n >> 6, hd = n & 63;
                    ((bf16*)Cout)[((size_t)(b * NH + h) * HD + hd) * LEN + s] = f2b(val);
                } else {
                    ((float*)Cout)[(size_t)m * DIM + n] = val;
                }
            }
        }
    }
}

#define QSCALE (0.125f * 1.44269504088896f)   // fold log2(e) for exp2

// batched projections: z = 0:q_b 1:k_b 2:vT 3:q_g 4:k_g(phrase)
__global__ __launch_bounds__(256) void gemm_proj(const bf16* __restrict__ qbf,
                                                 const bf16* __restrict__ phrasebf,
                                                 const bf16* __restrict__ wbf,
                                                 const float* __restrict__ bias_pack,
                                                 bf16* __restrict__ q_b, bf16* __restrict__ k_b,
                                                 bf16* __restrict__ vT, bf16* __restrict__ q_g,
                                                 bf16* __restrict__ k_g) {
    int z = blockIdx.z;
    const bf16* A = qbf;
    bf16* C;
    int mode = 0, LEN = SEQ;
    float scale = 1.0f;
    switch (z) {
        case 0: C = q_b; scale = QSCALE; break;
        case 1: C = k_b; break;
        case 2: C = vT; mode = 2; break;
        case 3: C = q_g; scale = QSCALE; break;
        default:
            if (blockIdx.x >= 4) return;          // M = 512 for phrase GEMM
            A = phrasebf; C = k_g; LEN = PN; break;
    }
    gemm_body(A, wbf + (size_t)z * DIM * DIM, bias_pack + z * DIM, C,
              blockIdx.x * 128, blockIdx.y * 128, scale, mode, LEN);
}

__global__ __launch_bounds__(256) void gemm_final(const bf16* __restrict__ attn_bf,
                                                  const bf16* __restrict__ wbf,
                                                  const float* __restrict__ bias_pack,
                                                  float* __restrict__ out) {
    gemm_body(attn_bf, wbf + (size_t)5 * DIM * DIM, bias_pack + 5 * DIM, out,
              blockIdx.x * 128, blockIdx.y * 128, 1.0f, 1, SEQ);
}

// ---------------------------------------------------------------------------
// MFMA attention v3: 64-row blocks (v1 occupancy), S computed TRANSPOSED
// (A=K,B=Q) so exp results pack as ds_write_b64 into row-major Ps[qrow][key];
// PV reads Ps back as b128 A-fragments.  Q fragments hoisted out of the
// chunk loop; K/V staging prefetched into VGPRs.
//   phase 0: gauss branch over PN phrase keys; phase 1: base over SEQ keys.
// Writes attn_bf bf16 [m=s*BSZ+b][h*64+hd].
// ---------------------------------------------------------------------------
__global__ __launch_bounds__(256) void attn_kernel(const bf16* __restrict__ qb,
                                                   const bf16* __restrict__ kb,
                                                   const bf16* __restrict__ vT,
                                                   const bf16* __restrict__ qg,
                                                   const bf16* __restrict__ kg,
                                                   const bf16* __restrict__ gvT,
                                                   bf16* __restrict__ out) {
    __shared__ bf16 Qs[64][72];    // [qrow][hd]
    __shared__ bf16 Ks[64][72];    // [key][hd]
    __shared__ bf16 Vt[64][72];    // [hd][key]
    __shared__ bf16 Ps[64][72];    // [qrow][key]  row-major

    int t = threadIdx.x;
    int wave = t >> 6, lane = t & 63;
    int l15 = lane & 15, quad = lane >> 4;
    int q0 = blockIdx.x * 64;
    int bh = blockIdx.y;
    int b = bh / NH, h = bh % NH;

    const short8 ones = (short8)0x3F80;   // bf16 1.0 splat

    float result[4][4] = {};              // [n-tile][row]

    for (int phase = 0; phase < 2; ++phase) {
        const bf16* qptr = phase ? qb : qg;
        const bf16* kptr = phase ? kb : kg;
        const bf16* vtp  = phase ? vT : gvT;
        int kvlen = phase ? SEQ : PN;
        int nchunk = kvlen / 64;

        __syncthreads();   // prior phase's Qs/Ps reads done
        {
            int r = t >> 2, c0 = (t & 3) * 16;
            const bf16* qsrc = qptr + ((size_t)bh * SEQ + q0 + r) * HD + c0;
            *(short8*)&Qs[r][c0]     = *(const short8*)qsrc;
            *(short8*)&Qs[r][c0 + 8] = *(const short8*)(qsrc + 8);
        }
        __syncthreads();   // Qs visible
        // hoist chunk-invariant Q B-fragments (this wave's 16 q-rows)
        short8 bq[2];
        bq[0] = *(short8*)&Qs[wave * 16 + l15][quad * 8];
        bq[1] = *(short8*)&Qs[wave * 16 + l15][32 + quad * 8];

        // staging addresses (sr = key idx for K, hd idx for V)
        int sr = t >> 2, sc = (t & 3) * 16;
        const bf16* kbase = kptr + ((size_t)bh * kvlen + sr) * HD + sc;
        const bf16* vbase = vtp + (size_t)(bh * HD + sr) * kvlen + sc;

        // prefetch chunk 0
        short8 kr0 = *(const short8*)(kbase);
        short8 kr1 = *(const short8*)(kbase + 8);
        short8 vr0 = *(const short8*)(vbase);
        short8 vr1 = *(const short8*)(vbase + 8);

        f32x4 o_acc[4] = {};
        f32x4 l_acc = {};
        for (int ch = 0; ch < nchunk; ++ch) {
            __syncthreads();   // prev chunk's Ks/Vt reads done
            *(short8*)&Ks[sr][sc]     = kr0;
            *(short8*)&Ks[sr][sc + 8] = kr1;
            *(short8*)&Vt[sr][sc]     = vr0;
            *(short8*)&Vt[sr][sc + 8] = vr1;
            if (ch + 1 < nchunk) {     // prefetch next chunk over compute
                const bf16* kn = kbase + (size_t)(ch + 1) * 64 * HD;
                const bf16* vn = vbase + (ch + 1) * 64;
                kr0 = *(const short8*)(kn);
                kr1 = *(const short8*)(kn + 8);
                vr0 = *(const short8*)(vn);
                vr1 = *(const short8*)(vn + 8);
            }
            __syncthreads();

            // S^T = K Q^T : D[m=key (4 tiles of 16)][n=qrow (this wave's 16)]
            f32x4 s_acc[4] = {};
#pragma unroll
            for (int kk = 0; kk < 2; ++kk) {
#pragma unroll
                for (int tn = 0; tn < 4; ++tn) {
                    short8 ak = *(short8*)&Ks[tn * 16 + l15][kk * 32 + quad * 8];
                    s_acc[tn] = __builtin_amdgcn_mfma_f32_16x16x32_bf16(ak, bq[kk], s_acc[tn], 0, 0, 0);
                }
            }
            // P = exp2(S): C-layout of S^T has col=qrow(l15), reg->key
            // -> 4 consecutive keys per tile: packed 8B store, row-major Ps
#pragma unroll
            for (int tn = 0; tn < 4; ++tn) {
                short4v pk;
#pragma unroll
                for (int r = 0; r < 4; ++r)
                    pk[r] = fbits(exp2f(fminf(s_acc[tn][r], 43.f)));
                *(short4v*)&Ps[wave * 16 + l15][tn * 16 + quad * 4] = pk;
            }
            // PV + rowsum: A = Ps rows (this wave's 16 qrows), B = Vt rows
#pragma unroll
            for (int kk = 0; kk < 2; ++kk) {
                short8 pa = *(short8*)&Ps[wave * 16 + l15][kk * 32 + quad * 8];
                l_acc = __builtin_amdgcn_mfma_f32_16x16x32_bf16(pa, ones, l_acc, 0, 0, 0);
#pragma unroll
                for (int tn = 0; tn < 4; ++tn) {
                    short8 vb = *(short8*)&Vt[tn * 16 + l15][kk * 32 + quad * 8];
                    o_acc[tn] = __builtin_amdgcn_mfma_f32_16x16x32_bf16(pa, vb, o_acc[tn], 0, 0, 0);
                }
            }
        }
#pragma unroll
        for (int r = 0; r < 4; ++r) {
            float inv = 0.5f / fmaxf(l_acc[r], 1e-30f);
#pragma unroll
            for (int tn = 0; tn < 4; ++tn)
                result[tn][r] += o_acc[tn][r] * inv;
        }
    }

    // store attn_bf; O C-layout: col=hd(l15), row=qrow quad*4+r
#pragma unroll
    for (int r = 0; r < 4; ++r) {
        int srow = q0 + wave * 16 + quad * 4 + r;
        int mm = srow * BSZ + b;
#pragma unroll
        for (int tn = 0; tn < 4; ++tn) {
            int dcol = h * HD + tn * 16 + l15;
            out[(size_t)mm * DIM + dcol] = f2b(result[tn][r]);
        }
    }
}

// ---------------------------------------------------------------------------
extern "C" void kernel_launch(void* const* d_in, const int* in_sizes, int n_in,
                              void* d_out, int out_size, void* d_ws, size_t ws_size,
                              hipStream_t stream) {
    (void)in_sizes; (void)n_in; (void)out_size; (void)ws_size;
    const float* query = (const float*)d_in[0];
    const float* Wq_b  = (const float*)d_in[1];
    const float* bq_b  = (const float*)d_in[2];
    const float* Wk_b  = (const float*)d_in[3];
    const float* bk_b  = (const float*)d_in[4];
    const float* Wq_g  = (const float*)d_in[5];
    const float* bq_g  = (const float*)d_in[6];
    const float* Wk_g  = (const float*)d_in[7];
    const float* bk_g  = (const float*)d_in[8];
    const float* Wv    = (const float*)d_in[9];
    const float* bv    = (const float*)d_in[10];
    const float* Wo    = (const float*)d_in[11];
    const float* bo    = (const float*)d_in[12];
    float* out = (float*)d_out;

    const size_t NQ = (size_t)BSZ * NH * SEQ * HD;   // 4194304
    const size_t NP = (size_t)BSZ * NH * PN * HD;    // 524288
    bf16* qbf      = (bf16*)d_ws;                    // 4M
    bf16* wbf      = qbf + NQ;                       // 6M
    bf16* phrasebf = wbf + (size_t)6 * DIM * DIM;    // 512K
    bf16* q_b      = phrasebf + (size_t)PN * BSZ * DIM;
    bf16* k_b      = q_b + NQ;
    bf16* vT       = k_b + NQ;                       // [bh][hd][s]
    bf16* q_g      = vT + NQ;
    bf16* k_g      = q_g + NQ;                       // [bh][p][hd]
    bf16* gvT      = k_g + NP;                       // [bh][hd][p]
    bf16* attn_bf  = gvT + NP;                       // [m][dcol]
    float* bias_pack = (float*)(attn_bf + NQ);       // 6*1024 fp32

    const int QV = (SEQ * BSZ * DIM) / 8, WV6 = 6 * (DIM * DIM) / 8;
    convert_kernel<<<(QV + WV6) / 256 + 3, 256, 0, stream>>>(
        query, Wq_b, Wk_b, Wv, Wq_g, Wk_g, Wo,
        bq_b, bk_b, bv, bq_g, bk_g, bo, qbf, wbf, bias_pack);
    phrase_max_kernel<<<(PN * BSZ * DIM) / 256, 256, 0, stream>>>(query, phrasebf);

    dim3 gp((SEQ * BSZ) / 128, DIM / 128, 5);
    gemm_proj<<<gp, 256, 0, stream>>>(qbf, phrasebf, wbf, bias_pack,
                                      q_b, k_b, vT, q_g, k_g);

    gauss_v_kernel<<<BSZ * NH * HD, PN, 0, stream>>>(vT, gvT);

    dim3 g3(SEQ / 64, BSZ * NH);
    attn_kernel<<<g3, 256, 0, stream>>>(q_b, k_b, vT, q_g, k_g, gvT, attn_bf);

    dim3 gf((SEQ * BSZ) / 128, DIM / 128);
    gemm_final<<<gf, 256, 0, stream>>>(attn_bf, wbf, bias_pack, out);
}

// Round 9
// 287.683 us; speedup vs baseline: 1.1298x; 1.0263x over previous
//
#include <hip/hip_runtime.h>
#include <hip/hip_bf16.h>

#define SEQ 2048
#define BSZ 2
#define DIM 1024
#define NH 16
#define HD 64
#define WIN 8
#define PN 256

typedef __hip_bfloat16 bf16;
typedef __attribute__((ext_vector_type(8))) short short8;
typedef __attribute__((ext_vector_type(4))) short short4v;
typedef __attribute__((ext_vector_type(4))) float f32x4;

__device__ __forceinline__ float b2f(bf16 x) { return __bfloat162float(x); }
__device__ __forceinline__ bf16 f2b(float x) { return __float2bfloat16(x); }
__device__ __forceinline__ short fbits(float x) { bf16 h = __float2bfloat16(x); return *(short*)&h; }

// async global->LDS, 16B per lane; LDS dest must be wave-uniform base + lane*16
__device__ __forceinline__ void gl_lds16(const bf16* g, bf16* l) {
    __builtin_amdgcn_global_load_lds((const __attribute__((address_space(1))) void*)g,
                                     (__attribute__((address_space(3))) void*)l, 16, 0, 0);
}

// ---------------------------------------------------------------------------
// fp32 -> bf16 pre-convert: query (4M) + 6 weights (6M) + bias pack (6K fp32)
// ---------------------------------------------------------------------------
__global__ void convert_kernel(const float* __restrict__ q,
                               const float* __restrict__ w0, const float* __restrict__ w1,
                               const float* __restrict__ w2, const float* __restrict__ w3,
                               const float* __restrict__ w4, const float* __restrict__ w5,
                               const float* __restrict__ b0, const float* __restrict__ b1,
                               const float* __restrict__ b2, const float* __restrict__ b3,
                               const float* __restrict__ b4, const float* __restrict__ b5,
                               bf16* __restrict__ qbf, bf16* __restrict__ wbf,
                               float* __restrict__ bp) {
    int i = blockIdx.x * 256 + threadIdx.x;          // vector idx, 8 floats each
    const int QV = (SEQ * BSZ * DIM) / 8;            // 524288
    const int WV = (DIM * DIM) / 8;                  // 131072
    const int TV = QV + 6 * WV;
    if (i >= TV) {                                   // bias path: 768 chunks
        int j = i - TV;
        if (j >= 768) return;
        int mat = j >> 7, k = (j & 127) * 8;
        const float* s = (mat == 0) ? b0 : (mat == 1) ? b1 : (mat == 2) ? b2
                       : (mat == 3) ? b3 : (mat == 4) ? b4 : b5;
        *(f32x4*)(bp + mat * DIM + k)     = *(const f32x4*)(s + k);
        *(f32x4*)(bp + mat * DIM + k + 4) = *(const f32x4*)(s + k + 4);
        return;
    }
    const float* src;
    bf16* dst;
    size_t off;
    if (i < QV) { src = q; dst = qbf; off = (size_t)i * 8; }
    else {
        int j = i - QV;
        int mat = j / WV, k = j - mat * WV;
        src = (mat == 0) ? w0 : (mat == 1) ? w1 : (mat == 2) ? w2
            : (mat == 3) ? w3 : (mat == 4) ? w4 : w5;
        dst = wbf + (size_t)mat * DIM * DIM;
        off = (size_t)k * 8;
    }
    f32x4 av4 = *(const f32x4*)(src + off);
    f32x4 bv4 = *(const f32x4*)(src + off + 4);
    short8 o;
#pragma unroll
    for (int e = 0; e < 4; ++e) { o[e] = fbits(av4[e]); o[e + 4] = fbits(bv4[e]); }
    *(short8*)(dst + off) = o;
}

// ---------------------------------------------------------------------------
// phrase[(p*BSZ+b)*DIM+d] = max_{w<8} query[(8p+w)][b][d]   (fp32 in, bf16 out)
// ---------------------------------------------------------------------------
__global__ void phrase_max_kernel(const float* __restrict__ q, bf16* __restrict__ phrase) {
    int idx = blockIdx.x * 256 + threadIdx.x;
    int d  = idx % DIM;
    int pb = idx / DIM;
    int b  = pb % BSZ;
    int p  = pb / BSZ;
    float m = -1e30f;
#pragma unroll
    for (int w = 0; w < WIN; ++w)
        m = fmaxf(m, q[((size_t)(p * WIN + w) * BSZ + b) * DIM + d]);
    phrase[idx] = f2b(m);
}

// ---------------------------------------------------------------------------
// gvT[bh*HD+hd][p] = sum_j gauss(p,j) * vT[bh*HD+hd][j], banded |j-mu|<=15.5
// ---------------------------------------------------------------------------
__global__ void gauss_v_kernel(const bf16* __restrict__ vT, bf16* __restrict__ gvT) {
    int row = blockIdx.x;               // bh*HD + hd
    int p   = threadIdx.x;              // 0..255
    float mu = p * (float)WIN + (WIN - 1) * 0.5f;
    float acc = 0.f;
    int j0 = p * WIN - 12;
    const bf16* src = vT + (size_t)row * SEQ;
#pragma unroll
    for (int jj = 0; jj < 32; ++jj) {
        int j = j0 + jj;
        if (j < 0 || j >= SEQ) continue;
        float dd = (float)j - mu;
        acc += __expf(-dd * dd * 0.125f) * 0.199471140200716f * b2f(src[j]);
    }
    gvT[(size_t)row * PN + p] = f2b(acc);
}

// ---------------------------------------------------------------------------
// 128x128 GEMM body (m97 pattern): C = (A @ Wtile^T + bias) * scale
// bf16 in via global_load_lds(16B), fp32 MFMA accum, LDS [128][32] unpadded.
// modes: 0 head-scatter bf16, 2 transposed head-scatter bf16.
// ---------------------------------------------------------------------------
__device__ __forceinline__ void gemm_body(const bf16* __restrict__ A,
                                          const bf16* __restrict__ W,
                                          const float* __restrict__ bias,
                                          void* __restrict__ Cout,
                                          int m0, int n0, float scale,
                                          int mode, int LEN) {
    __shared__ bf16 As[128 * 32];
    __shared__ bf16 Ws[128 * 32];
    int t = threadIdx.x;
    int wave = t >> 6, lane = t & 63;
    int wm = (wave >> 1) * 64, wn = (wave & 1) * 64;
    int l15 = lane & 15, quad = lane >> 4;

    f32x4 acc[4][4] = {};

    for (int k0 = 0; k0 < DIM; k0 += 32) {
        {
            int c0 = t, c1 = t + 256;
            gl_lds16(A + (size_t)(m0 + (c0 >> 2)) * DIM + k0 + (c0 & 3) * 8, &As[c0 * 8]);
            gl_lds16(A + (size_t)(m0 + (c1 >> 2)) * DIM + k0 + (c1 & 3) * 8, &As[c1 * 8]);
            gl_lds16(W + (size_t)(n0 + (c0 >> 2)) * DIM + k0 + (c0 & 3) * 8, &Ws[c0 * 8]);
            gl_lds16(W + (size_t)(n0 + (c1 >> 2)) * DIM + k0 + (c1 & 3) * 8, &Ws[c1 * 8]);
        }
        __syncthreads();
        short8 af[4], bfr[4];
#pragma unroll
        for (int tm = 0; tm < 4; ++tm)
            af[tm] = *(short8*)&As[(wm + tm * 16 + l15) * 32 + quad * 8];
#pragma unroll
        for (int tn = 0; tn < 4; ++tn)
            bfr[tn] = *(short8*)&Ws[(wn + tn * 16 + l15) * 32 + quad * 8];
#pragma unroll
        for (int tm = 0; tm < 4; ++tm)
#pragma unroll
            for (int tn = 0; tn < 4; ++tn)
                acc[tm][tn] = __builtin_amdgcn_mfma_f32_16x16x32_bf16(af[tm], bfr[tn], acc[tm][tn], 0, 0, 0);
        __syncthreads();
    }

#pragma unroll
    for (int tm = 0; tm < 4; ++tm) {
        int mrow = m0 + wm + tm * 16 + quad * 4;
#pragma unroll
        for (int tn = 0; tn < 4; ++tn) {
            int n = n0 + wn + tn * 16 + l15;
            float bsv = bias[n];
#pragma unroll
            for (int r = 0; r < 4; ++r) {
                int m = mrow + r;
                float val = (acc[tm][tn][r] + bsv) * scale;
                int s = m / BSZ, b = m % BSZ;
                int h = n >> 6, hd = n & 63;
                if (mode == 0)
                    ((bf16*)Cout)[((size_t)(b * NH + h) * LEN + s) * HD + hd] = f2b(val);
                else
                    ((bf16*)Cout)[((size_t)(b * NH + h) * HD + hd) * LEN + s] = f2b(val);
            }
        }
    }
}

#define QSCALE (0.125f * 1.44269504088896f)   // fold log2(e) for exp2

// batched projections: z = 0:q_b 1:k_b 2:vT 3:q_g 4:k_g(phrase)
__global__ __launch_bounds__(256) void gemm_proj(const bf16* __restrict__ qbf,
                                                 const bf16* __restrict__ phrasebf,
                                                 const bf16* __restrict__ wbf,
                                                 const float* __restrict__ bias_pack,
                                                 bf16* __restrict__ q_b, bf16* __restrict__ k_b,
                                                 bf16* __restrict__ vT, bf16* __restrict__ q_g,
                                                 bf16* __restrict__ k_g) {
    int z = blockIdx.z;
    const bf16* A = qbf;
    bf16* C;
    int mode = 0, LEN = SEQ;
    float scale = 1.0f;
    switch (z) {
        case 0: C = q_b; scale = QSCALE; break;
        case 1: C = k_b; break;
        case 2: C = vT; mode = 2; break;
        case 3: C = q_g; scale = QSCALE; break;
        default:
            if (blockIdx.x >= 4) return;          // M = 512 for phrase GEMM
            A = phrasebf; C = k_g; LEN = PN; break;
    }
    gemm_body(A, wbf + (size_t)z * DIM * DIM, bias_pack + z * DIM, C,
              blockIdx.x * 128, blockIdx.y * 128, scale, mode, LEN);
}

// ---------------------------------------------------------------------------
// final GEMM: out = attn_bf @ Wo^T + bo (fp32), 64x128 tile -> 512 blocks
// (2 blocks/CU; the 128x128 grid was 256 blocks = 1/CU = latency-bound).
// 4 waves: wave (wm 0/32, wn 0/64) owns 32x64 via 2x4 mfma tiles.
// ---------------------------------------------------------------------------
__global__ __launch_bounds__(256) void gemm_final(const bf16* __restrict__ A,
                                                  const bf16* __restrict__ wbf,
                                                  const float* __restrict__ bias_pack,
                                                  float* __restrict__ out) {
    __shared__ bf16 As[64 * 32];
    __shared__ bf16 Ws[128 * 32];
    const bf16* W = wbf + (size_t)5 * DIM * DIM;
    const float* bias = bias_pack + 5 * DIM;
    int t = threadIdx.x;
    int m0 = blockIdx.x * 64, n0 = blockIdx.y * 128;
    int wave = t >> 6, lane = t & 63;
    int wm = (wave >> 1) * 32, wn = (wave & 1) * 64;
    int l15 = lane & 15, quad = lane >> 4;

    f32x4 acc[2][4] = {};

    for (int k0 = 0; k0 < DIM; k0 += 32) {
        {
            int c0 = t, c1 = t + 256;     // Ws: 512 chunks; As: 256 chunks
            gl_lds16(A + (size_t)(m0 + (c0 >> 2)) * DIM + k0 + (c0 & 3) * 8, &As[c0 * 8]);
            gl_lds16(W + (size_t)(n0 + (c0 >> 2)) * DIM + k0 + (c0 & 3) * 8, &Ws[c0 * 8]);
            gl_lds16(W + (size_t)(n0 + (c1 >> 2)) * DIM + k0 + (c1 & 3) * 8, &Ws[c1 * 8]);
        }
        __syncthreads();
        short8 af[2], bfr[4];
#pragma unroll
        for (int tm = 0; tm < 2; ++tm)
            af[tm] = *(short8*)&As[(wm + tm * 16 + l15) * 32 + quad * 8];
#pragma unroll
        for (int tn = 0; tn < 4; ++tn)
            bfr[tn] = *(short8*)&Ws[(wn + tn * 16 + l15) * 32 + quad * 8];
#pragma unroll
        for (int tm = 0; tm < 2; ++tm)
#pragma unroll
            for (int tn = 0; tn < 4; ++tn)
                acc[tm][tn] = __builtin_amdgcn_mfma_f32_16x16x32_bf16(af[tm], bfr[tn], acc[tm][tn], 0, 0, 0);
        __syncthreads();
    }

#pragma unroll
    for (int tm = 0; tm < 2; ++tm) {
        int mrow = m0 + wm + tm * 16 + quad * 4;
#pragma unroll
        for (int tn = 0; tn < 4; ++tn) {
            int n = n0 + wn + tn * 16 + l15;
            float bsv = bias[n];
#pragma unroll
            for (int r = 0; r < 4; ++r)
                out[(size_t)(mrow + r) * DIM + n] = acc[tm][tn][r] + bsv;
        }
    }
}

// ---------------------------------------------------------------------------
// MFMA attention v3.1: 64-row blocks; S computed transposed (A=K,B=Q) so exp
// packs as 8B stores into row-major P; Q fragments hoisted to registers per
// phase, letting P ALIAS the Q buffer (LDS 36.9 -> 27.6 KB). K/V staging
// VGPR-prefetched.  No exp clamp (scores bounded, see round-8 notes).
// ---------------------------------------------------------------------------
__global__ __launch_bounds__(256) void attn_kernel(const bf16* __restrict__ qb,
                                                   const bf16* __restrict__ kb,
                                                   const bf16* __restrict__ vT,
                                                   const bf16* __restrict__ qg,
                                                   const bf16* __restrict__ kg,
                                                   const bf16* __restrict__ gvT,
                                                   bf16* __restrict__ out) {
    __shared__ bf16 QPs[64][72];   // Q during hoist, then Ps[qrow][key]
    __shared__ bf16 Ks[64][72];    // [key][hd]
    __shared__ bf16 Vt[64][72];    // [hd][key]

    int t = threadIdx.x;
    int wave = t >> 6, lane = t & 63;
    int l15 = lane & 15, quad = lane >> 4;
    int q0 = blockIdx.x * 64;
    int bh = blockIdx.y;
    int b = bh / NH, h = bh % NH;

    const short8 ones = (short8)0x3F80;   // bf16 1.0 splat

    float result[4][4] = {};              // [n-tile][row]

    for (int phase = 0; phase < 2; ++phase) {
        const bf16* qptr = phase ? qb : qg;
        const bf16* kptr = phase ? kb : kg;
        const bf16* vtp  = phase ? vT : gvT;
        int kvlen = phase ? SEQ : PN;
        int nchunk = kvlen / 64;

        __syncthreads();   // prior phase's Ps reads done before Q restage
        {
            int r = t >> 2, c0 = (t & 3) * 16;
            const bf16* qsrc = qptr + ((size_t)bh * SEQ + q0 + r) * HD + c0;
            *(short8*)&QPs[r][c0]     = *(const short8*)qsrc;
            *(short8*)&QPs[r][c0 + 8] = *(const short8*)(qsrc + 8);
        }
        __syncthreads();   // Q visible
        // hoist chunk-invariant Q B-fragments (this wave's 16 q-rows)
        short8 bq[2];
        bq[0] = *(short8*)&QPs[wave * 16 + l15][quad * 8];
        bq[1] = *(short8*)&QPs[wave * 16 + l15][32 + quad * 8];
        // NOTE: every wave passes the chunk-0 loop-top barrier only after its
        // bq hoist, so Ps writes (post 2nd barrier) can safely reuse QPs.

        int sr = t >> 2, sc = (t & 3) * 16;
        const bf16* kbase = kptr + ((size_t)bh * kvlen + sr) * HD + sc;
        const bf16* vbase = vtp + (size_t)(bh * HD + sr) * kvlen + sc;

        // prefetch chunk 0
        short8 kr0 = *(const short8*)(kbase);
        short8 kr1 = *(const short8*)(kbase + 8);
        short8 vr0 = *(const short8*)(vbase);
        short8 vr1 = *(const short8*)(vbase + 8);

        f32x4 o_acc[4] = {};
        f32x4 l_acc = {};
        for (int ch = 0; ch < nchunk; ++ch) {
            __syncthreads();   // prev chunk's Ks/Vt reads done
            *(short8*)&Ks[sr][sc]     = kr0;
            *(short8*)&Ks[sr][sc + 8] = kr1;
            *(short8*)&Vt[sr][sc]     = vr0;
            *(short8*)&Vt[sr][sc + 8] = vr1;
            if (ch + 1 < nchunk) {     // prefetch next chunk over compute
                const bf16* kn = kbase + (size_t)(ch + 1) * 64 * HD;
                const bf16* vn = vbase + (ch + 1) * 64;
                kr0 = *(const short8*)(kn);
                kr1 = *(const short8*)(kn + 8);
                vr0 = *(const short8*)(vn);
                vr1 = *(const short8*)(vn + 8);
            }
            __syncthreads();

            // S^T = K Q^T : D[m=key (4 tiles of 16)][n=qrow (this wave's 16)]
            f32x4 s_acc[4] = {};
#pragma unroll
            for (int kk = 0; kk < 2; ++kk) {
#pragma unroll
                for (int tn = 0; tn < 4; ++tn) {
                    short8 ak = *(short8*)&Ks[tn * 16 + l15][kk * 32 + quad * 8];
                    s_acc[tn] = __builtin_amdgcn_mfma_f32_16x16x32_bf16(ak, bq[kk], s_acc[tn], 0, 0, 0);
                }
            }
            // P = exp2(S^T): col=qrow(l15), reg->key -> packed 8B row-major store
#pragma unroll
            for (int tn = 0; tn < 4; ++tn) {
                short4v pk;
#pragma unroll
                for (int r = 0; r < 4; ++r)
                    pk[r] = fbits(exp2f(s_acc[tn][r]));
                *(short4v*)&QPs[wave * 16 + l15][tn * 16 + quad * 4] = pk;
            }
            // PV + rowsum: A = Ps rows (this wave's 16 qrows), B = Vt rows
#pragma unroll
            for (int kk = 0; kk < 2; ++kk) {
                short8 pa = *(short8*)&QPs[wave * 16 + l15][kk * 32 + quad * 8];
                l_acc = __builtin_amdgcn_mfma_f32_16x16x32_bf16(pa, ones, l_acc, 0, 0, 0);
#pragma unroll
                for (int tn = 0; tn < 4; ++tn) {
                    short8 vb = *(short8*)&Vt[tn * 16 + l15][kk * 32 + quad * 8];
                    o_acc[tn] = __builtin_amdgcn_mfma_f32_16x16x32_bf16(pa, vb, o_acc[tn], 0, 0, 0);
                }
            }
        }
#pragma unroll
        for (int r = 0; r < 4; ++r) {
            float inv = 0.5f / fmaxf(l_acc[r], 1e-30f);
#pragma unroll
            for (int tn = 0; tn < 4; ++tn)
                result[tn][r] += o_acc[tn][r] * inv;
        }
    }

    // store attn_bf; O C-layout: col=hd(l15), row=qrow quad*4+r
#pragma unroll
    for (int r = 0; r < 4; ++r) {
        int srow = q0 + wave * 16 + quad * 4 + r;
        int mm = srow * BSZ + b;
#pragma unroll
        for (int tn = 0; tn < 4; ++tn) {
            int dcol = h * HD + tn * 16 + l15;
            out[(size_t)mm * DIM + dcol] = f2b(result[tn][r]);
        }
    }
}

// ---------------------------------------------------------------------------
extern "C" void kernel_launch(void* const* d_in, const int* in_sizes, int n_in,
                              void* d_out, int out_size, void* d_ws, size_t ws_size,
                              hipStream_t stream) {
    (void)in_sizes; (void)n_in; (void)out_size; (void)ws_size;
    const float* query = (const float*)d_in[0];
    const float* Wq_b  = (const float*)d_in[1];
    const float* bq_b  = (const float*)d_in[2];
    const float* Wk_b  = (const float*)d_in[3];
    const float* bk_b  = (const float*)d_in[4];
    const float* Wq_g  = (const float*)d_in[5];
    const float* bq_g  = (const float*)d_in[6];
    const float* Wk_g  = (const float*)d_in[7];
    const float* bk_g  = (const float*)d_in[8];
    const float* Wv    = (const float*)d_in[9];
    const float* bv    = (const float*)d_in[10];
    const float* Wo    = (const float*)d_in[11];
    const float* bo    = (const float*)d_in[12];
    float* out = (float*)d_out;

    const size_t NQ = (size_t)BSZ * NH * SEQ * HD;   // 4194304
    const size_t NP = (size_t)BSZ * NH * PN * HD;    // 524288
    bf16* qbf      = (bf16*)d_ws;                    // 4M
    bf16* wbf      = qbf + NQ;                       // 6M
    bf16* phrasebf = wbf + (size_t)6 * DIM * DIM;    // 512K
    bf16* q_b      = phrasebf + (size_t)PN * BSZ * DIM;
    bf16* k_b      = q_b + NQ;
    bf16* vT       = k_b + NQ;                       // [bh][hd][s]
    bf16* q_g      = vT + NQ;
    bf16* k_g      = q_g + NQ;                       // [bh][p][hd]
    bf16* gvT      = k_g + NP;                       // [bh][hd][p]
    bf16* attn_bf  = gvT + NP;                       // [m][dcol]
    float* bias_pack = (float*)(attn_bf + NQ);       // 6*1024 fp32

    const int QV = (SEQ * BSZ * DIM) / 8, WV6 = 6 * (DIM * DIM) / 8;
    convert_kernel<<<(QV + WV6) / 256 + 3, 256, 0, stream>>>(
        query, Wq_b, Wk_b, Wv, Wq_g, Wk_g, Wo,
        bq_b, bk_b, bv, bq_g, bk_g, bo, qbf, wbf, bias_pack);
    phrase_max_kernel<<<(PN * BSZ * DIM) / 256, 256, 0, stream>>>(query, phrasebf);

    dim3 gp((SEQ * BSZ) / 128, DIM / 128, 5);
    gemm_proj<<<gp, 256, 0, stream>>>(qbf, phrasebf, wbf, bias_pack,
                                      q_b, k_b, vT, q_g, k_g);

    gauss_v_kernel<<<BSZ * NH * HD, PN, 0, stream>>>(vT, gvT);

    dim3 g3(SEQ / 64, BSZ * NH);
    attn_kernel<<<g3, 256, 0, stream>>>(q_b, k_b, vT, q_g, k_g, gvT, attn_bf);

    dim3 gf((SEQ * BSZ) / 64, DIM / 128);
    gemm_final<<<gf, 256, 0, stream>>>(attn_bf, wbf, bias_pack, out);
}

// Round 10
// 274.940 us; speedup vs baseline: 1.1821x; 1.0464x over previous
//
#include <hip/hip_runtime.h>
#include <hip/hip_bf16.h>

#define SEQ 2048
#define BSZ 2
#define DIM 1024
#define NH 16
#define HD 64
#define WIN 8
#define PN 256

typedef __hip_bfloat16 bf16;
typedef __attribute__((ext_vector_type(8))) short short8;
typedef __attribute__((ext_vector_type(4))) short short4v;
typedef __attribute__((ext_vector_type(4))) float f32x4;

__device__ __forceinline__ float b2f(bf16 x) { return __bfloat162float(x); }
__device__ __forceinline__ bf16 f2b(float x) { return __float2bfloat16(x); }
__device__ __forceinline__ short fbits(float x) { bf16 h = __float2bfloat16(x); return *(short*)&h; }

// async global->LDS, 16B per lane; LDS dest must be wave-uniform base + lane*16
__device__ __forceinline__ void gl_lds16(const bf16* g, bf16* l) {
    __builtin_amdgcn_global_load_lds((const __attribute__((address_space(1))) void*)g,
                                     (__attribute__((address_space(3))) void*)l, 16, 0, 0);
}

// ---------------------------------------------------------------------------
// fp32 -> bf16 pre-convert: query (4M) + 6 weights (6M) + bias pack (6K fp32)
// ---------------------------------------------------------------------------
__global__ void convert_kernel(const float* __restrict__ q,
                               const float* __restrict__ w0, const float* __restrict__ w1,
                               const float* __restrict__ w2, const float* __restrict__ w3,
                               const float* __restrict__ w4, const float* __restrict__ w5,
                               const float* __restrict__ b0, const float* __restrict__ b1,
                               const float* __restrict__ b2, const float* __restrict__ b3,
                               const float* __restrict__ b4, const float* __restrict__ b5,
                               bf16* __restrict__ qbf, bf16* __restrict__ wbf,
                               float* __restrict__ bp) {
    int i = blockIdx.x * 256 + threadIdx.x;          // vector idx, 8 floats each
    const int QV = (SEQ * BSZ * DIM) / 8;            // 524288
    const int WV = (DIM * DIM) / 8;                  // 131072
    const int TV = QV + 6 * WV;
    if (i >= TV) {                                   // bias path: 768 chunks
        int j = i - TV;
        if (j >= 768) return;
        int mat = j >> 7, k = (j & 127) * 8;
        const float* s = (mat == 0) ? b0 : (mat == 1) ? b1 : (mat == 2) ? b2
                       : (mat == 3) ? b3 : (mat == 4) ? b4 : b5;
        *(f32x4*)(bp + mat * DIM + k)     = *(const f32x4*)(s + k);
        *(f32x4*)(bp + mat * DIM + k + 4) = *(const f32x4*)(s + k + 4);
        return;
    }
    const float* src;
    bf16* dst;
    size_t off;
    if (i < QV) { src = q; dst = qbf; off = (size_t)i * 8; }
    else {
        int j = i - QV;
        int mat = j / WV, k = j - mat * WV;
        src = (mat == 0) ? w0 : (mat == 1) ? w1 : (mat == 2) ? w2
            : (mat == 3) ? w3 : (mat == 4) ? w4 : w5;
        dst = wbf + (size_t)mat * DIM * DIM;
        off = (size_t)k * 8;
    }
    f32x4 av4 = *(const f32x4*)(src + off);
    f32x4 bv4 = *(const f32x4*)(src + off + 4);
    short8 o;
#pragma unroll
    for (int e = 0; e < 4; ++e) { o[e] = fbits(av4[e]); o[e + 4] = fbits(bv4[e]); }
    *(short8*)(dst + off) = o;
}

// ---------------------------------------------------------------------------
// phrase[(p*BSZ+b)*DIM+d] = max_{w<8} query[(8p+w)][b][d]   (fp32 in, bf16 out)
// ---------------------------------------------------------------------------
__global__ void phrase_max_kernel(const float* __restrict__ q, bf16* __restrict__ phrase) {
    int idx = blockIdx.x * 256 + threadIdx.x;
    int d  = idx % DIM;
    int pb = idx / DIM;
    int b  = pb % BSZ;
    int p  = pb / BSZ;
    float m = -1e30f;
#pragma unroll
    for (int w = 0; w < WIN; ++w)
        m = fmaxf(m, q[((size_t)(p * WIN + w) * BSZ + b) * DIM + d]);
    phrase[idx] = f2b(m);
}

// ---------------------------------------------------------------------------
// gvT[bh*HD+hd][p] = sum_j gauss(p,j) * vT[bh*HD+hd][j], banded |j-mu|<=15.5
// ---------------------------------------------------------------------------
__global__ void gauss_v_kernel(const bf16* __restrict__ vT, bf16* __restrict__ gvT) {
    int row = blockIdx.x;               // bh*HD + hd
    int p   = threadIdx.x;              // 0..255
    float mu = p * (float)WIN + (WIN - 1) * 0.5f;
    float acc = 0.f;
    int j0 = p * WIN - 12;
    const bf16* src = vT + (size_t)row * SEQ;
#pragma unroll
    for (int jj = 0; jj < 32; ++jj) {
        int j = j0 + jj;
        if (j < 0 || j >= SEQ) continue;
        float dd = (float)j - mu;
        acc += __expf(-dd * dd * 0.125f) * 0.199471140200716f * b2f(src[j]);
    }
    gvT[(size_t)row * PN + p] = f2b(acc);
}

// ---------------------------------------------------------------------------
// 128x128 GEMM body (m97 pattern): C = (A @ Wtile^T + bias) * scale
// bf16 in via global_load_lds(16B), fp32 MFMA accum, LDS [128][32] unpadded.
// modes: 0 head-scatter bf16, 2 transposed head-scatter bf16.
// ---------------------------------------------------------------------------
__device__ __forceinline__ void gemm_body(const bf16* __restrict__ A,
                                          const bf16* __restrict__ W,
                                          const float* __restrict__ bias,
                                          void* __restrict__ Cout,
                                          int m0, int n0, float scale,
                                          int mode, int LEN) {
    __shared__ bf16 As[128 * 32];
    __shared__ bf16 Ws[128 * 32];
    int t = threadIdx.x;
    int wave = t >> 6, lane = t & 63;
    int wm = (wave >> 1) * 64, wn = (wave & 1) * 64;
    int l15 = lane & 15, quad = lane >> 4;

    f32x4 acc[4][4] = {};

    for (int k0 = 0; k0 < DIM; k0 += 32) {
        {
            int c0 = t, c1 = t + 256;
            gl_lds16(A + (size_t)(m0 + (c0 >> 2)) * DIM + k0 + (c0 & 3) * 8, &As[c0 * 8]);
            gl_lds16(A + (size_t)(m0 + (c1 >> 2)) * DIM + k0 + (c1 & 3) * 8, &As[c1 * 8]);
            gl_lds16(W + (size_t)(n0 + (c0 >> 2)) * DIM + k0 + (c0 & 3) * 8, &Ws[c0 * 8]);
            gl_lds16(W + (size_t)(n0 + (c1 >> 2)) * DIM + k0 + (c1 & 3) * 8, &Ws[c1 * 8]);
        }
        __syncthreads();
        short8 af[4], bfr[4];
#pragma unroll
        for (int tm = 0; tm < 4; ++tm)
            af[tm] = *(short8*)&As[(wm + tm * 16 + l15) * 32 + quad * 8];
#pragma unroll
        for (int tn = 0; tn < 4; ++tn)
            bfr[tn] = *(short8*)&Ws[(wn + tn * 16 + l15) * 32 + quad * 8];
#pragma unroll
        for (int tm = 0; tm < 4; ++tm)
#pragma unroll
            for (int tn = 0; tn < 4; ++tn)
                acc[tm][tn] = __builtin_amdgcn_mfma_f32_16x16x32_bf16(af[tm], bfr[tn], acc[tm][tn], 0, 0, 0);
        __syncthreads();
    }

#pragma unroll
    for (int tm = 0; tm < 4; ++tm) {
        int mrow = m0 + wm + tm * 16 + quad * 4;
#pragma unroll
        for (int tn = 0; tn < 4; ++tn) {
            int n = n0 + wn + tn * 16 + l15;
            float bsv = bias[n];
#pragma unroll
            for (int r = 0; r < 4; ++r) {
                int m = mrow + r;
                float val = (acc[tm][tn][r] + bsv) * scale;
                int s = m / BSZ, b = m % BSZ;
                int h = n >> 6, hd = n & 63;
                if (mode == 0)
                    ((bf16*)Cout)[((size_t)(b * NH + h) * LEN + s) * HD + hd] = f2b(val);
                else
                    ((bf16*)Cout)[((size_t)(b * NH + h) * HD + hd) * LEN + s] = f2b(val);
            }
        }
    }
}

#define QSCALE (0.125f * 1.44269504088896f)   // fold log2(e) for exp2

// batched projections: z = 0:q_b 1:k_b 2:vT 3:q_g 4:k_g(phrase)
__global__ __launch_bounds__(256) void gemm_proj(const bf16* __restrict__ qbf,
                                                 const bf16* __restrict__ phrasebf,
                                                 const bf16* __restrict__ wbf,
                                                 const float* __restrict__ bias_pack,
                                                 bf16* __restrict__ q_b, bf16* __restrict__ k_b,
                                                 bf16* __restrict__ vT, bf16* __restrict__ q_g,
                                                 bf16* __restrict__ k_g) {
    int z = blockIdx.z;
    const bf16* A = qbf;
    bf16* C;
    int mode = 0, LEN = SEQ;
    float scale = 1.0f;
    switch (z) {
        case 0: C = q_b; scale = QSCALE; break;
        case 1: C = k_b; break;
        case 2: C = vT; mode = 2; break;
        case 3: C = q_g; scale = QSCALE; break;
        default:
            if (blockIdx.x >= 4) return;          // M = 512 for phrase GEMM
            A = phrasebf; C = k_g; LEN = PN; break;
    }
    gemm_body(A, wbf + (size_t)z * DIM * DIM, bias_pack + z * DIM, C,
              blockIdx.x * 128, blockIdx.y * 128, scale, mode, LEN);
}

// ---------------------------------------------------------------------------
// final GEMM: out = attn_bf @ Wo^T + bo (fp32), 64x128 tile -> 512 blocks.
// ---------------------------------------------------------------------------
__global__ __launch_bounds__(256) void gemm_final(const bf16* __restrict__ A,
                                                  const bf16* __restrict__ wbf,
                                                  const float* __restrict__ bias_pack,
                                                  float* __restrict__ out) {
    __shared__ bf16 As[64 * 32];
    __shared__ bf16 Ws[128 * 32];
    const bf16* W = wbf + (size_t)5 * DIM * DIM;
    const float* bias = bias_pack + 5 * DIM;
    int t = threadIdx.x;
    int m0 = blockIdx.x * 64, n0 = blockIdx.y * 128;
    int wave = t >> 6, lane = t & 63;
    int wm = (wave >> 1) * 32, wn = (wave & 1) * 64;
    int l15 = lane & 15, quad = lane >> 4;

    f32x4 acc[2][4] = {};

    for (int k0 = 0; k0 < DIM; k0 += 32) {
        {
            int c0 = t, c1 = t + 256;
            gl_lds16(A + (size_t)(m0 + (c0 >> 2)) * DIM + k0 + (c0 & 3) * 8, &As[c0 * 8]);
            gl_lds16(W + (size_t)(n0 + (c0 >> 2)) * DIM + k0 + (c0 & 3) * 8, &Ws[c0 * 8]);
            gl_lds16(W + (size_t)(n0 + (c1 >> 2)) * DIM + k0 + (c1 & 3) * 8, &Ws[c1 * 8]);
        }
        __syncthreads();
        short8 af[2], bfr[4];
#pragma unroll
        for (int tm = 0; tm < 2; ++tm)
            af[tm] = *(short8*)&As[(wm + tm * 16 + l15) * 32 + quad * 8];
#pragma unroll
        for (int tn = 0; tn < 4; ++tn)
            bfr[tn] = *(short8*)&Ws[(wn + tn * 16 + l15) * 32 + quad * 8];
#pragma unroll
        for (int tm = 0; tm < 2; ++tm)
#pragma unroll
            for (int tn = 0; tn < 4; ++tn)
                acc[tm][tn] = __builtin_amdgcn_mfma_f32_16x16x32_bf16(af[tm], bfr[tn], acc[tm][tn], 0, 0, 0);
        __syncthreads();
    }

#pragma unroll
    for (int tm = 0; tm < 2; ++tm) {
        int mrow = m0 + wm + tm * 16 + quad * 4;
#pragma unroll
        for (int tn = 0; tn < 4; ++tn) {
            int n = n0 + wn + tn * 16 + l15;
            float bsv = bias[n];
#pragma unroll
            for (int r = 0; r < 4; ++r)
                out[(size_t)(mrow + r) * DIM + n] = acc[tm][tn][r] + bsv;
        }
    }
}

// ---------------------------------------------------------------------------
// MFMA attention v4: 128-row blocks, 4 waves x 32 qrows (2 n-tiles in S^T).
// K/V fragment reads amortized 2x; S^T packed-b64 P round-trip; P aliases
// the wave's OWN Q rows (no cross-wave hazard); K/V staging VGPR-prefetched.
// LDS 36.9 KB.  No exp clamp (scores bounded; see round-8 notes).
// ---------------------------------------------------------------------------
__global__ __launch_bounds__(256) void attn_kernel(const bf16* __restrict__ qb,
                                                   const bf16* __restrict__ kb,
                                                   const bf16* __restrict__ vT,
                                                   const bf16* __restrict__ qg,
                                                   const bf16* __restrict__ kg,
                                                   const bf16* __restrict__ gvT,
                                                   bf16* __restrict__ out) {
    __shared__ bf16 QPs[128][72];  // Q during hoist, then Ps[qrow][key]
    __shared__ bf16 Ks[64][72];    // [key][hd]
    __shared__ bf16 Vt[64][72];    // [hd][key]

    int t = threadIdx.x;
    int wave = t >> 6, lane = t & 63;
    int l15 = lane & 15, quad = lane >> 4;
    int q0 = blockIdx.x * 128;
    int bh = blockIdx.y;
    int b = bh / NH, h = bh % NH;

    const short8 ones = (short8)0x3F80;   // bf16 1.0 splat

    float result[2][4][4] = {};           // [q-tile][n-tile][row]

    for (int phase = 0; phase < 2; ++phase) {
        const bf16* qptr = phase ? qb : qg;
        const bf16* kptr = phase ? kb : kg;
        const bf16* vtp  = phase ? vT : gvT;
        int kvlen = phase ? SEQ : PN;
        int nchunk = kvlen / 64;

        __syncthreads();   // prior phase's P reads done before Q restage
        {
            int r = t >> 1, c0 = (t & 1) * 32;
            const bf16* qsrc = qptr + ((size_t)bh * SEQ + q0 + r) * HD + c0;
#pragma unroll
            for (int e = 0; e < 4; ++e)
                *(short8*)&QPs[r][c0 + e * 8] = *(const short8*)(qsrc + e * 8);
        }
        __syncthreads();   // Q visible
        // hoist chunk-invariant Q B-fragments (this wave's 32 q-rows)
        short8 bq[2][2];   // [q-tile][kk]
#pragma unroll
        for (int qt = 0; qt < 2; ++qt) {
            bq[qt][0] = *(short8*)&QPs[wave * 32 + qt * 16 + l15][quad * 8];
            bq[qt][1] = *(short8*)&QPs[wave * 32 + qt * 16 + l15][32 + quad * 8];
        }
        // (each wave's P region == its own Q rows; no cross-wave QPs hazard)

        int sr = t >> 2, sc = (t & 3) * 16;
        const bf16* kbase = kptr + ((size_t)bh * kvlen + sr) * HD + sc;
        const bf16* vbase = vtp + (size_t)(bh * HD + sr) * kvlen + sc;

        // prefetch chunk 0
        short8 kr0 = *(const short8*)(kbase);
        short8 kr1 = *(const short8*)(kbase + 8);
        short8 vr0 = *(const short8*)(vbase);
        short8 vr1 = *(const short8*)(vbase + 8);

        f32x4 o_acc[2][4] = {};
        f32x4 l_acc[2] = {};
        for (int ch = 0; ch < nchunk; ++ch) {
            __syncthreads();   // prev chunk's Ks/Vt reads done
            *(short8*)&Ks[sr][sc]     = kr0;
            *(short8*)&Ks[sr][sc + 8] = kr1;
            *(short8*)&Vt[sr][sc]     = vr0;
            *(short8*)&Vt[sr][sc + 8] = vr1;
            if (ch + 1 < nchunk) {     // prefetch next chunk over compute
                const bf16* kn = kbase + (size_t)(ch + 1) * 64 * HD;
                const bf16* vn = vbase + (ch + 1) * 64;
                kr0 = *(const short8*)(kn);
                kr1 = *(const short8*)(kn + 8);
                vr0 = *(const short8*)(vn);
                vr1 = *(const short8*)(vn + 8);
            }
            __syncthreads();

            // S^T = K Q^T : D[m=key (4 tiles)][n=qrow (2 tiles of 16)]
            f32x4 s_acc[2][4] = {};
#pragma unroll
            for (int kk = 0; kk < 2; ++kk) {
#pragma unroll
                for (int tn = 0; tn < 4; ++tn) {
                    short8 ak = *(short8*)&Ks[tn * 16 + l15][kk * 32 + quad * 8];
                    s_acc[0][tn] = __builtin_amdgcn_mfma_f32_16x16x32_bf16(ak, bq[0][kk], s_acc[0][tn], 0, 0, 0);
                    s_acc[1][tn] = __builtin_amdgcn_mfma_f32_16x16x32_bf16(ak, bq[1][kk], s_acc[1][tn], 0, 0, 0);
                }
            }
            // P = exp2(S^T): col=qrow(l15), reg->key -> packed 8B row-major store
#pragma unroll
            for (int qt = 0; qt < 2; ++qt)
#pragma unroll
                for (int tn = 0; tn < 4; ++tn) {
                    short4v pk;
#pragma unroll
                    for (int r = 0; r < 4; ++r)
                        pk[r] = fbits(exp2f(s_acc[qt][tn][r]));
                    *(short4v*)&QPs[wave * 32 + qt * 16 + l15][tn * 16 + quad * 4] = pk;
                }
            // PV + rowsum: A = P rows, B = Vt rows (V-frags reused across q-tiles)
#pragma unroll
            for (int kk = 0; kk < 2; ++kk) {
                short8 pa0 = *(short8*)&QPs[wave * 32 + l15][kk * 32 + quad * 8];
                short8 pa1 = *(short8*)&QPs[wave * 32 + 16 + l15][kk * 32 + quad * 8];
                l_acc[0] = __builtin_amdgcn_mfma_f32_16x16x32_bf16(pa0, ones, l_acc[0], 0, 0, 0);
                l_acc[1] = __builtin_amdgcn_mfma_f32_16x16x32_bf16(pa1, ones, l_acc[1], 0, 0, 0);
#pragma unroll
                for (int tn = 0; tn < 4; ++tn) {
                    short8 vb = *(short8*)&Vt[tn * 16 + l15][kk * 32 + quad * 8];
                    o_acc[0][tn] = __builtin_amdgcn_mfma_f32_16x16x32_bf16(pa0, vb, o_acc[0][tn], 0, 0, 0);
                    o_acc[1][tn] = __builtin_amdgcn_mfma_f32_16x16x32_bf16(pa1, vb, o_acc[1][tn], 0, 0, 0);
                }
            }
        }
#pragma unroll
        for (int qt = 0; qt < 2; ++qt)
#pragma unroll
            for (int r = 0; r < 4; ++r) {
                float inv = 0.5f / fmaxf(l_acc[qt][r], 1e-30f);
#pragma unroll
                for (int tn = 0; tn < 4; ++tn)
                    result[qt][tn][r] += o_acc[qt][tn][r] * inv;
            }
    }

    // store attn_bf; O C-layout: col=hd(l15), row=qrow quad*4+r
#pragma unroll
    for (int qt = 0; qt < 2; ++qt)
#pragma unroll
        for (int r = 0; r < 4; ++r) {
            int srow = q0 + wave * 32 + qt * 16 + quad * 4 + r;
            int mm = srow * BSZ + b;
#pragma unroll
            for (int tn = 0; tn < 4; ++tn) {
                int dcol = h * HD + tn * 16 + l15;
                out[(size_t)mm * DIM + dcol] = f2b(result[qt][tn][r]);
            }
        }
}

// ---------------------------------------------------------------------------
extern "C" void kernel_launch(void* const* d_in, const int* in_sizes, int n_in,
                              void* d_out, int out_size, void* d_ws, size_t ws_size,
                              hipStream_t stream) {
    (void)in_sizes; (void)n_in; (void)out_size; (void)ws_size;
    const float* query = (const float*)d_in[0];
    const float* Wq_b  = (const float*)d_in[1];
    const float* bq_b  = (const float*)d_in[2];
    const float* Wk_b  = (const float*)d_in[3];
    const float* bk_b  = (const float*)d_in[4];
    const float* Wq_g  = (const float*)d_in[5];
    const float* bq_g  = (const float*)d_in[6];
    const float* Wk_g  = (const float*)d_in[7];
    const float* bk_g  = (const float*)d_in[8];
    const float* Wv    = (const float*)d_in[9];
    const float* bv    = (const float*)d_in[10];
    const float* Wo    = (const float*)d_in[11];
    const float* bo    = (const float*)d_in[12];
    float* out = (float*)d_out;

    const size_t NQ = (size_t)BSZ * NH * SEQ * HD;   // 4194304
    const size_t NP = (size_t)BSZ * NH * PN * HD;    // 524288
    bf16* qbf      = (bf16*)d_ws;                    // 4M
    bf16* wbf      = qbf + NQ;                       // 6M
    bf16* phrasebf = wbf + (size_t)6 * DIM * DIM;    // 512K
    bf16* q_b      = phrasebf + (size_t)PN * BSZ * DIM;
    bf16* k_b      = q_b + NQ;
    bf16* vT       = k_b + NQ;                       // [bh][hd][s]
    bf16* q_g      = vT + NQ;
    bf16* k_g      = q_g + NQ;                       // [bh][p][hd]
    bf16* gvT      = k_g + NP;                       // [bh][hd][p]
    bf16* attn_bf  = gvT + NP;                       // [m][dcol]
    float* bias_pack = (float*)(attn_bf + NQ);       // 6*1024 fp32

    const int QV = (SEQ * BSZ * DIM) / 8, WV6 = 6 * (DIM * DIM) / 8;
    convert_kernel<<<(QV + WV6) / 256 + 3, 256, 0, stream>>>(
        query, Wq_b, Wk_b, Wv, Wq_g, Wk_g, Wo,
        bq_b, bk_b, bv, bq_g, bk_g, bo, qbf, wbf, bias_pack);
    phrase_max_kernel<<<(PN * BSZ * DIM) / 256, 256, 0, stream>>>(query, phrasebf);

    dim3 gp((SEQ * BSZ) / 128, DIM / 128, 5);
    gemm_proj<<<gp, 256, 0, stream>>>(qbf, phrasebf, wbf, bias_pack,
                                      q_b, k_b, vT, q_g, k_g);

    gauss_v_kernel<<<BSZ * NH * HD, PN, 0, stream>>>(vT, gvT);

    dim3 g3(SEQ / 128, BSZ * NH);
    attn_kernel<<<g3, 256, 0, stream>>>(q_b, k_b, vT, q_g, k_g, gvT, attn_bf);

    dim3 gf((SEQ * BSZ) / 64, DIM / 128);
    gemm_final<<<gf, 256, 0, stream>>>(attn_bf, wbf, bias_pack, out);
}